// Round 2
// baseline (597.661 us; speedup 1.0000x reference)
//
#include <hip/hip_runtime.h>

#define B   8
#define S   16
#define C   32
#define P   64
#define E   768
#define M   512        // S*C
#define LL  32768      // M*P
#define NE  1000000
#define TR  100000     // emb table rows

typedef __attribute__((ext_vector_type(8))) short short8;   // 8 bf16 = 4 VGPRs
typedef __attribute__((ext_vector_type(4))) float f32x4;    // MFMA C/D frag

// RNE float -> bf16 (data has no NaN)
__device__ __forceinline__ short f2bf(float x) {
    unsigned u = __float_as_uint(x);
    u += 0x7FFFu + ((u >> 16) & 1u);
    return (short)(u >> 16);
}

__device__ __forceinline__ short8 pack8(float4 lo, float4 hi) {
    short8 r;
    r[0] = f2bf(lo.x); r[1] = f2bf(lo.y); r[2] = f2bf(lo.z); r[3] = f2bf(lo.w);
    r[4] = f2bf(hi.x); r[5] = f2bf(hi.y); r[6] = f2bf(hi.z); r[7] = f2bf(hi.w);
    return r;
}

// ---------------------------------------------------------------------------
// k_pre: span (128 x 768 fp32) -> bf16, row-major (B matrix for k0)
// ---------------------------------------------------------------------------
__global__ __launch_bounds__(256) void k_pre_spanbf(
    const float* __restrict__ span, short* __restrict__ spanbf)
{
    const int i = blockIdx.x * 256 + threadIdx.x;
    if (i < B * S * E) spanbf[i] = f2bf(span[i]);
}

// ---------------------------------------------------------------------------
// k0: dot_table[t][n] = dot(emb[t], span_flat[n]),  t<100000, n<128 (b*16+s)
// bf16 MFMA 16x16x32. Block = 4 waves, 128 rows x 128 cols per block.
// Each wave: 32 rows (2 row-tiles) x 8 col-tiles. Reads emb exactly once.
// A frag: lane holds A[m=lane&15][k0 + (lane>>4)*8 + j], j=0..7
// B frag: lane holds B[k][n=lane&15], same k pattern  (B[k][n] = span[n][k])
// C/D:    col=lane&15, row=(lane>>4)*4+reg   [verified m89/m91]
// ---------------------------------------------------------------------------
__global__ __launch_bounds__(256) void k0_dot_table(
    const float* __restrict__ emb,      // (TR, 768)
    const short* __restrict__ spanbf,   // (128, 768) bf16
    float*       __restrict__ dt)       // (TR, 128)
{
    const int wave = threadIdx.x >> 6;
    const int lane = threadIdx.x & 63;
    const int mrow = lane & 15;
    const int kq   = lane >> 4;
    const int rbase = blockIdx.x * 128 + wave * 32;

    const int r0 = rbase + mrow;
    const int r1 = r0 + 16;
    const float* a0p = emb + (size_t)(r0 < TR ? r0 : 0) * E;
    const float* a1p = emb + (size_t)(r1 < TR ? r1 : 0) * E;

    f32x4 acc[2][8];
    #pragma unroll
    for (int i = 0; i < 2; ++i)
        #pragma unroll
        for (int j = 0; j < 8; ++j)
            acc[i][j] = f32x4{0.f, 0.f, 0.f, 0.f};

    for (int k0 = 0; k0 < E; k0 += 32) {
        const int koff = k0 + kq * 8;
        const float4 a0lo = *(const float4*)(a0p + koff);
        const float4 a0hi = *(const float4*)(a0p + koff + 4);
        const float4 a1lo = *(const float4*)(a1p + koff);
        const float4 a1hi = *(const float4*)(a1p + koff + 4);
        const short8 A0 = pack8(a0lo, a0hi);
        const short8 A1 = pack8(a1lo, a1hi);
        #pragma unroll
        for (int ct = 0; ct < 8; ++ct) {
            const short8 Bf = *(const short8*)(spanbf + (size_t)(ct * 16 + mrow) * E + koff);
            acc[0][ct] = __builtin_amdgcn_mfma_f32_16x16x32_bf16(A0, Bf, acc[0][ct], 0, 0, 0);
            acc[1][ct] = __builtin_amdgcn_mfma_f32_16x16x32_bf16(A1, Bf, acc[1][ct], 0, 0, 0);
        }
    }

    #pragma unroll
    for (int rt = 0; rt < 2; ++rt) {
        const int orow = rbase + rt * 16 + kq * 4;
        #pragma unroll
        for (int r = 0; r < 4; ++r) {
            if (orow + r < TR) {
                float* o = dt + (size_t)(orow + r) * 128 + mrow;
                #pragma unroll
                for (int ct = 0; ct < 8; ++ct) o[ct * 16] = acc[rt][ct][r];
            }
        }
    }
}

// ---------------------------------------------------------------------------
// k1: sum1[b,m] = sum_p att[b,m*64+p] * dot_table[ids[b,m*64+p]][b*16 + m%16]
// One wave per segment; lane p handles one bag member; shuffle-reduce.
// ---------------------------------------------------------------------------
__global__ __launch_bounds__(256) void k1_bagdot(
    const float* __restrict__ dt,      // (TR, 128)
    const int*   __restrict__ ids,     // (B, LL)
    const float* __restrict__ att,     // (B, LL)
    float*       __restrict__ sum1)    // (B*M)
{
    const int seg  = blockIdx.x * 4 + (threadIdx.x >> 6);
    const int lane = threadIdx.x & 63;
    const int b = seg >> 9;
    const int m = seg & 511;
    const int n = (b << 4) | (m & 15);

    const size_t base = (size_t)b * LL + (size_t)m * P;
    const int   id = ids[base + lane];
    const float a  = att[base + lane];
    float v = a * dt[(size_t)id * 128 + n];

    #pragma unroll
    for (int off = 32; off > 0; off >>= 1)
        v += __shfl_down(v, off, 64);
    if (lane == 0) sum1[seg] = v;
}

// ---------------------------------------------------------------------------
// k2: per-batch fused: span_scores -> softmax(S) -> softmax(M) -> cand,
// branch-free dedup over duplicate qids, denominator of the 1M softmax,
// owner values sval = exp(sum_dupes)*invden. No global atomics.
// ---------------------------------------------------------------------------
__global__ __launch_bounds__(512) void k2_fused(
    const float* __restrict__ sum1,    // (B, 512)
    const float* __restrict__ span,    // (B, 16, 768)
    const float* __restrict__ spanW,   // (768)
    const float* __restrict__ spanb,   // (1)
    const int*   __restrict__ qids,    // (B, 512)
    float*       __restrict__ sval,    // (B, 512) owner value or 0
    float*       __restrict__ invden)  // (B)
{
    const int b = blockIdx.x;
    const int t = threadIdx.x;

    __shared__ float ls[512];
    __shared__ float cs[512];
    __shared__ int   qs[512];
    __shared__ float ss[16];
    __shared__ float inv_s;

    // span_scores: 16 groups of 32 threads
    {
        const int s = t >> 5, j = t & 31;
        const float* sp = span + (size_t)(b * S + s) * E;
        float partial = 0.f;
        for (int e = j; e < E; e += 32) partial = fmaf(sp[e], spanW[e], partial);
        #pragma unroll
        for (int off = 16; off > 0; off >>= 1) partial += __shfl_down(partial, off, 32);
        if (j == 0) ss[s] = partial + spanb[0];
    }

    const float v = sum1[b * M + t];
    ls[t] = v;
    qs[t] = qids[b * M + t];
    __syncthreads();

    // softmax over s (16 values at stride 32) for this thread's column
    const int c = t & 31;
    float mx = -1e30f;
    #pragma unroll
    for (int s2 = 0; s2 < S; ++s2) mx = fmaxf(mx, ls[s2 * 32 + c]);
    float den = 0.f;
    #pragma unroll
    for (int s2 = 0; s2 < S; ++s2) den += expf(ls[s2 * 32 + c] - mx);
    const float m2 = ss[t >> 5] * (expf(v - mx) / den);
    __syncthreads();

    // softmax over 512
    ls[t] = m2; __syncthreads();
    for (int off = 256; off > 0; off >>= 1) {
        if (t < off) ls[t] = fmaxf(ls[t], ls[t + off]);
        __syncthreads();
    }
    const float bigM = ls[0];
    __syncthreads();
    const float ex = expf(m2 - bigM);
    ls[t] = ex; __syncthreads();
    for (int off = 256; off > 0; off >>= 1) {
        if (t < off) ls[t] += ls[t + off];
        __syncthreads();
    }
    const float cand = ex / ls[0];
    __syncthreads();

    cs[t] = cand; __syncthreads();

    // branch-free dedup scan (LDS broadcast reads, fully pipelined)
    const int myq = qs[t];
    float dsum = 0.f;
    int first = 512;
    #pragma unroll 8
    for (int j = 0; j < 512; ++j) {
        const bool match = (qs[j] == myq);
        dsum += match ? cs[j] : 0.f;
        if (match && j < first) first = j;
    }
    const bool owner = (first == t) && (myq < NE);
    const float ev = owner ? expf(dsum) : 1.f;

    ls[t] = owner ? (ev - 1.f) : 0.f;
    __syncthreads();
    for (int off = 256; off > 0; off >>= 1) {
        if (t < off) ls[t] += ls[t + off];
        __syncthreads();
    }
    if (t == 0) {
        const float iv = 1.f / (1.0e6f + ls[0]);
        invden[b] = iv;
        inv_s = iv;
    }
    __syncthreads();

    sval[b * M + t] = owner ? ev * inv_s : 0.f;
}

// ---------------------------------------------------------------------------
// k3: out[b][i] = invden[b] everywhere (write-only, float4). exp(0)=1 baseline.
// ---------------------------------------------------------------------------
__global__ __launch_bounds__(256) void k3_fill(
    float* __restrict__ out, const float* __restrict__ invden)
{
    const int i = blockIdx.x * 256 + threadIdx.x;   // over B*NE/4 = 2M float4
    if (i >= (B * NE) / 4) return;
    const float v = invden[i / (NE / 4)];
    reinterpret_cast<float4*>(out)[i] = make_float4(v, v, v, v);
}

// ---------------------------------------------------------------------------
// k4: scatter owner values over the fill (<=4096 dword stores).
// ---------------------------------------------------------------------------
__global__ __launch_bounds__(512) void k4_scatter(
    const float* __restrict__ sval, const int* __restrict__ qids,
    float* __restrict__ out)
{
    const int b = blockIdx.x, t = threadIdx.x;
    const float v = sval[b * M + t];
    const int   q = qids[b * M + t];
    if (v > 0.f && q < NE) out[(size_t)b * NE + q] = v;
}

extern "C" void kernel_launch(void* const* d_in, const int* in_sizes, int n_in,
                              void* d_out, int out_size, void* d_ws, size_t ws_size,
                              hipStream_t stream)
{
    (void)in_sizes; (void)n_in; (void)out_size; (void)ws_size;

    const float* span_embs = (const float*)d_in[0];  // (B,S,E)
    const int*   ids       = (const int*)  d_in[1];  // (B,LL)
    // d_in[2]: offsets_tr — fixed arange(M)*P structure, not needed
    const float* att       = (const float*)d_in[3];  // (B,LL)
    const int*   qids      = (const int*)  d_in[4];  // (B,M)
    const float* emb       = (const float*)d_in[5];  // (T,E)
    const float* spanW     = (const float*)d_in[6];  // (E)
    const float* spanb     = (const float*)d_in[7];  // (1)

    float* out = (float*)d_out;

    // workspace layout (needs ~51.3 MB; ws is ~1.2 GB per poison-fill counters)
    float* dt     = (float*)d_ws;                 // TR*128 floats = 51.2 MB
    float* sum1   = dt + (size_t)TR * 128;        // 4096
    float* sval   = sum1 + B * M;                 // 4096
    float* invden = sval + B * M;                 // 8
    short* spanbf = (short*)(invden + 64);        // 98304 bf16

    k_pre_spanbf<<<(B * S * E + 255) / 256, 256, 0, stream>>>(span_embs, spanbf);
    k0_dot_table<<<(TR + 127) / 128, 256, 0, stream>>>(emb, spanbf, dt);
    k1_bagdot<<<(B * M) / 4, 256, 0, stream>>>(dt, ids, att, sum1);
    k2_fused<<<B, 512, 0, stream>>>(sum1, span_embs, spanW, spanb, qids, sval, invden);
    k3_fill<<<((B * NE / 4) + 255) / 256, 256, 0, stream>>>(out, invden);
    k4_scatter<<<B, 512, 0, stream>>>(sval, qids, out);
}

// Round 3
// 523.784 us; speedup vs baseline: 1.1410x; 1.1410x over previous
//
#include <hip/hip_runtime.h>

#define B   8
#define S   16
#define C   32
#define P   64
#define E   768
#define M   512        // S*C
#define LL  32768      // M*P
#define NE  1000000
#define TR  100000     // emb table rows
#define KI  24         // E/32 k-iterations

typedef __attribute__((ext_vector_type(8))) short short8;   // 8 bf16 = 4 VGPRs
typedef __attribute__((ext_vector_type(4))) float f32x4;    // MFMA C/D frag

// RNE float -> bf16 (data has no NaN)
__device__ __forceinline__ short f2bf(float x) {
    unsigned u = __float_as_uint(x);
    u += 0x7FFFu + ((u >> 16) & 1u);
    return (short)(u >> 16);
}

__device__ __forceinline__ short8 pack8(float4 lo, float4 hi) {
    short8 r;
    r[0] = f2bf(lo.x); r[1] = f2bf(lo.y); r[2] = f2bf(lo.z); r[3] = f2bf(lo.w);
    r[4] = f2bf(hi.x); r[5] = f2bf(hi.y); r[6] = f2bf(hi.z); r[7] = f2bf(hi.w);
    return r;
}

// ---------------------------------------------------------------------------
// k_pre_bfrag: repack span (128 x 768 fp32) into MFMA B-fragment order:
// Bfrag[kk][ct][lane] (short8): element j = span[(ct*16+(lane&15))*E + kk*32
// + (lane>>4)*8 + j].  Makes every B-frag load in k0 a single coalesced
// 16 B/lane transaction. 24*8*64 = 12288 frags = 196 KB (L2-resident).
// ---------------------------------------------------------------------------
__global__ __launch_bounds__(256) void k_pre_bfrag(
    const float* __restrict__ span, short8* __restrict__ bfrag)
{
    const int idx = blockIdx.x * 256 + threadIdx.x;
    if (idx >= KI * 8 * 64) return;
    const int lane = idx & 63;
    const int ct   = (idx >> 6) & 7;
    const int kk   = idx >> 9;
    const int n = ct * 16 + (lane & 15);
    const int k = kk * 32 + (lane >> 4) * 8;
    const float* sp = span + (size_t)n * E + k;
    const float4 lo = *(const float4*)sp;
    const float4 hi = *(const float4*)(sp + 4);
    bfrag[idx] = pack8(lo, hi);
}

// ---------------------------------------------------------------------------
// k0: dt[t][n] = dot(emb[t], span_flat[n]), t<100000, n<128.
// Block = 256 thr / 4 waves, 128 rows x 128 cols. A staged global->LDS
// (bf16, double-buffered, frag-order layout), B from repacked frag tensor.
// A frag: lane holds A[m=lane&15][kq*8+j]; C/D: col=lane&15, row=kq*4+reg.
// ---------------------------------------------------------------------------
__global__ __launch_bounds__(256, 3) void k0_dot_table(
    const float* __restrict__ emb,      // (TR, 768)
    const short8* __restrict__ bfrag,   // (KI, 8, 64)
    float*       __restrict__ dt)       // (TR, 128)
{
    const int tid  = threadIdx.x;
    const int wave = tid >> 6;
    const int lane = tid & 63;
    const int mrow = lane & 15;
    const int kq   = lane >> 4;
    const int rbase = blockIdx.x * 128;

    // A fragments, double-buffered: [buf][rt][lane] -> 16 B each, 2 x 8 KB
    __shared__ short8 Abuf[2][8][64];

    // staging decomposition: 4 passes x (32 rows x 8 float4) per pass
    const int srow  = tid >> 3;   // 0..31 : row within pass
    const int kpart = tid & 7;    // float4 index within the 32-float k-slice
    const int dlane = (kpart >> 1) * 16;            // frag-lane base (needs +row&15)
    const int dsub  = (kpart & 1) * 4;              // short offset within short8

    f32x4 acc[2][8];
    #pragma unroll
    for (int i = 0; i < 2; ++i)
        #pragma unroll
        for (int j = 0; j < 8; ++j)
            acc[i][j] = f32x4{0.f, 0.f, 0.f, 0.f};

    // prologue: stage kk=0 into buf 0
    #pragma unroll
    for (int p = 0; p < 4; ++p) {
        const int row  = p * 32 + srow;
        int grow = rbase + row; if (grow >= TR) grow = TR - 1;
        const float4 v = *(const float4*)(emb + (size_t)grow * E + kpart * 4);
        short* dst = (short*)&Abuf[0][row >> 4][dlane + (row & 15)] + dsub;
        dst[0] = f2bf(v.x); dst[1] = f2bf(v.y); dst[2] = f2bf(v.z); dst[3] = f2bf(v.w);
    }
    __syncthreads();

    for (int kk = 0; kk < KI; ++kk) {
        const int buf = kk & 1;

        // A frags from LDS (conflict-free: lane*16 sequential)
        const short8 A0 = Abuf[buf][wave * 2][lane];
        const short8 A1 = Abuf[buf][wave * 2 + 1][lane];

        // B frags: coalesced 16 B/lane, L2-hot
        short8 Bf[8];
        #pragma unroll
        for (int ct = 0; ct < 8; ++ct)
            Bf[ct] = bfrag[(kk * 8 + ct) * 64 + lane];

        // prefetch next A slice into registers (independent of MFMAs below)
        float4 nv[4];
        if (kk + 1 < KI) {
            #pragma unroll
            for (int p = 0; p < 4; ++p) {
                const int row = p * 32 + srow;
                int grow = rbase + row; if (grow >= TR) grow = TR - 1;
                nv[p] = *(const float4*)(emb + (size_t)grow * E + (kk + 1) * 32 + kpart * 4);
            }
        }

        #pragma unroll
        for (int ct = 0; ct < 8; ++ct) {
            acc[0][ct] = __builtin_amdgcn_mfma_f32_16x16x32_bf16(A0, Bf[ct], acc[0][ct], 0, 0, 0);
            acc[1][ct] = __builtin_amdgcn_mfma_f32_16x16x32_bf16(A1, Bf[ct], acc[1][ct], 0, 0, 0);
        }

        // convert + store prefetched slice into the other buffer
        if (kk + 1 < KI) {
            #pragma unroll
            for (int p = 0; p < 4; ++p) {
                const int row = p * 32 + srow;
                short* dst = (short*)&Abuf[buf ^ 1][row >> 4][dlane + (row & 15)] + dsub;
                dst[0] = f2bf(nv[p].x); dst[1] = f2bf(nv[p].y);
                dst[2] = f2bf(nv[p].z); dst[3] = f2bf(nv[p].w);
            }
        }
        __syncthreads();
    }

    // epilogue: wave w owns row-tiles 2w, 2w+1
    #pragma unroll
    for (int rt = 0; rt < 2; ++rt) {
        const int orow = rbase + (wave * 2 + rt) * 16 + kq * 4;
        #pragma unroll
        for (int r = 0; r < 4; ++r) {
            if (orow + r < TR) {
                float* o = dt + (size_t)(orow + r) * 128 + mrow;
                #pragma unroll
                for (int ct = 0; ct < 8; ++ct) o[ct * 16] = acc[rt][ct][r];
            }
        }
    }
}

// ---------------------------------------------------------------------------
// k1: sum1[b,m] = sum_p att[b,m*64+p] * dt[ids[b,m*64+p]][b*16 + m%16]
// ---------------------------------------------------------------------------
__global__ __launch_bounds__(256) void k1_bagdot(
    const float* __restrict__ dt,      // (TR, 128)
    const int*   __restrict__ ids,     // (B, LL)
    const float* __restrict__ att,     // (B, LL)
    float*       __restrict__ sum1)    // (B*M)
{
    const int seg  = blockIdx.x * 4 + (threadIdx.x >> 6);
    const int lane = threadIdx.x & 63;
    const int b = seg >> 9;
    const int m = seg & 511;
    const int n = (b << 4) | (m & 15);

    const size_t base = (size_t)b * LL + (size_t)m * P;
    const int   id = ids[base + lane];
    const float a  = att[base + lane];
    float v = a * dt[(size_t)id * 128 + n];

    #pragma unroll
    for (int off = 32; off > 0; off >>= 1)
        v += __shfl_down(v, off, 64);
    if (lane == 0) sum1[seg] = v;
}

// ---------------------------------------------------------------------------
// k2: per-batch fused: span_scores -> softmax(S) -> softmax(M) -> cand,
// branch-free dedup over duplicate qids, denominator of the 1M softmax,
// owner values sval = exp(sum_dupes)*invden. No global atomics.
// ---------------------------------------------------------------------------
__global__ __launch_bounds__(512) void k2_fused(
    const float* __restrict__ sum1,    // (B, 512)
    const float* __restrict__ span,    // (B, 16, 768)
    const float* __restrict__ spanW,   // (768)
    const float* __restrict__ spanb,   // (1)
    const int*   __restrict__ qids,    // (B, 512)
    float*       __restrict__ sval,    // (B, 512) owner value or 0
    float*       __restrict__ invden)  // (B)
{
    const int b = blockIdx.x;
    const int t = threadIdx.x;

    __shared__ float ls[512];
    __shared__ float cs[512];
    __shared__ int   qs[512];
    __shared__ float ss[16];
    __shared__ float inv_s;

    // span_scores: 16 groups of 32 threads
    {
        const int s = t >> 5, j = t & 31;
        const float* sp = span + (size_t)(b * S + s) * E;
        float partial = 0.f;
        for (int e = j; e < E; e += 32) partial = fmaf(sp[e], spanW[e], partial);
        #pragma unroll
        for (int off = 16; off > 0; off >>= 1) partial += __shfl_down(partial, off, 32);
        if (j == 0) ss[s] = partial + spanb[0];
    }

    const float v = sum1[b * M + t];
    ls[t] = v;
    qs[t] = qids[b * M + t];
    __syncthreads();

    // softmax over s (16 values at stride 32) for this thread's column
    const int c = t & 31;
    float mx = -1e30f;
    #pragma unroll
    for (int s2 = 0; s2 < S; ++s2) mx = fmaxf(mx, ls[s2 * 32 + c]);
    float den = 0.f;
    #pragma unroll
    for (int s2 = 0; s2 < S; ++s2) den += expf(ls[s2 * 32 + c] - mx);
    const float m2 = ss[t >> 5] * (expf(v - mx) / den);
    __syncthreads();

    // softmax over 512
    ls[t] = m2; __syncthreads();
    for (int off = 256; off > 0; off >>= 1) {
        if (t < off) ls[t] = fmaxf(ls[t], ls[t + off]);
        __syncthreads();
    }
    const float bigM = ls[0];
    __syncthreads();
    const float ex = expf(m2 - bigM);
    ls[t] = ex; __syncthreads();
    for (int off = 256; off > 0; off >>= 1) {
        if (t < off) ls[t] += ls[t + off];
        __syncthreads();
    }
    const float cand = ex / ls[0];
    __syncthreads();

    cs[t] = cand; __syncthreads();

    // branch-free dedup scan (LDS broadcast reads, fully pipelined)
    const int myq = qs[t];
    float dsum = 0.f;
    int first = 512;
    #pragma unroll 8
    for (int j = 0; j < 512; ++j) {
        const bool match = (qs[j] == myq);
        dsum += match ? cs[j] : 0.f;
        if (match && j < first) first = j;
    }
    const bool owner = (first == t) && (myq < NE);
    const float ev = owner ? expf(dsum) : 1.f;

    ls[t] = owner ? (ev - 1.f) : 0.f;
    __syncthreads();
    for (int off = 256; off > 0; off >>= 1) {
        if (t < off) ls[t] += ls[t + off];
        __syncthreads();
    }
    if (t == 0) {
        const float iv = 1.f / (1.0e6f + ls[0]);
        invden[b] = iv;
        inv_s = iv;
    }
    __syncthreads();

    sval[b * M + t] = owner ? ev * inv_s : 0.f;
}

// ---------------------------------------------------------------------------
// k3: out[b][i] = invden[b] everywhere (write-only, float4). exp(0)=1 baseline.
// ---------------------------------------------------------------------------
__global__ __launch_bounds__(256) void k3_fill(
    float* __restrict__ out, const float* __restrict__ invden)
{
    const int i = blockIdx.x * 256 + threadIdx.x;   // over B*NE/4 = 2M float4
    if (i >= (B * NE) / 4) return;
    const float v = invden[i / (NE / 4)];
    reinterpret_cast<float4*>(out)[i] = make_float4(v, v, v, v);
}

// ---------------------------------------------------------------------------
// k4: scatter owner values over the fill (<=4096 dword stores).
// ---------------------------------------------------------------------------
__global__ __launch_bounds__(512) void k4_scatter(
    const float* __restrict__ sval, const int* __restrict__ qids,
    float* __restrict__ out)
{
    const int b = blockIdx.x, t = threadIdx.x;
    const float v = sval[b * M + t];
    const int   q = qids[b * M + t];
    if (v > 0.f && q < NE) out[(size_t)b * NE + q] = v;
}

extern "C" void kernel_launch(void* const* d_in, const int* in_sizes, int n_in,
                              void* d_out, int out_size, void* d_ws, size_t ws_size,
                              hipStream_t stream)
{
    (void)in_sizes; (void)n_in; (void)out_size; (void)ws_size;

    const float* span_embs = (const float*)d_in[0];  // (B,S,E)
    const int*   ids       = (const int*)  d_in[1];  // (B,LL)
    // d_in[2]: offsets_tr — fixed arange(M)*P structure, not needed
    const float* att       = (const float*)d_in[3];  // (B,LL)
    const int*   qids      = (const int*)  d_in[4];  // (B,M)
    const float* emb       = (const float*)d_in[5];  // (T,E)
    const float* spanW     = (const float*)d_in[6];  // (E)
    const float* spanb     = (const float*)d_in[7];  // (1)

    float* out = (float*)d_out;

    // workspace layout (~51.5 MB)
    float*  dt     = (float*)d_ws;                 // TR*128 floats = 51.2 MB
    float*  sum1   = dt + (size_t)TR * 128;        // 4096
    float*  sval   = sum1 + B * M;                 // 4096
    float*  invden = sval + B * M;                 // 8 (+pad)
    short8* bfrag  = (short8*)(invden + 64);       // 12288 * 16 B = 196 KB

    k_pre_bfrag<<<(KI * 8 * 64 + 255) / 256, 256, 0, stream>>>(span_embs, bfrag);
    k0_dot_table<<<(TR + 127) / 128, 256, 0, stream>>>(emb, bfrag, dt);
    k1_bagdot<<<(B * M) / 4, 256, 0, stream>>>(dt, ids, att, sum1);
    k2_fused<<<B, 512, 0, stream>>>(sum1, span_embs, spanW, spanb, qids, sval, invden);
    k3_fill<<<((B * NE / 4) + 255) / 256, 256, 0, stream>>>(out, invden);
    k4_scatter<<<B, 512, 0, stream>>>(sval, qids, out);
}

// Round 4
// 521.154 us; speedup vs baseline: 1.1468x; 1.0050x over previous
//
#include <hip/hip_runtime.h>

#define B   8
#define S   16
#define C   32
#define P   64
#define E   768
#define M   512        // S*C
#define LL  32768      // M*P
#define NE  1000000
#define TR  100000     // emb table rows
#define KI  24         // E/32 k-iterations

typedef __attribute__((ext_vector_type(8))) short short8;   // 8 bf16 = 4 VGPRs
typedef __attribute__((ext_vector_type(4))) float f32x4;    // MFMA C/D frag

// RNE float -> bf16 (data has no NaN)
__device__ __forceinline__ short f2bf(float x) {
    unsigned u = __float_as_uint(x);
    u += 0x7FFFu + ((u >> 16) & 1u);
    return (short)(u >> 16);
}

__device__ __forceinline__ short8 pack8(float4 lo, float4 hi) {
    short8 r;
    r[0] = f2bf(lo.x); r[1] = f2bf(lo.y); r[2] = f2bf(lo.z); r[3] = f2bf(lo.w);
    r[4] = f2bf(hi.x); r[5] = f2bf(hi.y); r[6] = f2bf(hi.z); r[7] = f2bf(hi.w);
    return r;
}

// async global->LDS DMA, 16 B/lane; LDS dest = base + lane*16 (wave-uniform base)
__device__ __forceinline__ void gl_lds16(const float* g, float* l) {
    __builtin_amdgcn_global_load_lds(
        (const __attribute__((address_space(1))) unsigned int*)g,
        (__attribute__((address_space(3))) unsigned int*)l,
        16, 0, 0);
}

// ---------------------------------------------------------------------------
// k_pre_bfrag: repack span (128 x 768 fp32) into MFMA B-fragment order:
// Bfrag[kk][ct][lane] (short8): element j = span[(ct*16+(lane&15))*E + kk*32
// + (lane>>4)*8 + j].  196 KB, L2-resident for k0.
// ---------------------------------------------------------------------------
__global__ __launch_bounds__(256) void k_pre_bfrag(
    const float* __restrict__ span, short8* __restrict__ bfrag)
{
    const int idx = blockIdx.x * 256 + threadIdx.x;
    if (idx >= KI * 8 * 64) return;
    const int lane = idx & 63;
    const int ct   = (idx >> 6) & 7;
    const int kk   = idx >> 9;
    const int n = ct * 16 + (lane & 15);
    const int k = kk * 32 + (lane >> 4) * 8;
    const float* sp = span + (size_t)n * E + k;
    const float4 lo = *(const float4*)sp;
    const float4 hi = *(const float4*)(sp + 4);
    bfrag[idx] = pack8(lo, hi);
}

// ---------------------------------------------------------------------------
// k0: dt[t][n] = dot(emb[t], span_flat[n]), t<100000, n<128.
// 256 thr / 4 waves, 128 rows x 128 cols per block. A staged fp32 via
// global_load_lds DMA (double-buffered 2x16KB, XOR-swizzled), bf16 convert
// after ds_read. B from repacked frag tensor (L2-hot).
// LDS swizzle: slot s of row r holds global col16 (s ^ (r&7)) of the 32-float
// k-slice -> staging coalesced AND frag ds_read_b128 2-way-only conflicts.
// A frag: lane holds A[m=lane&15][kq*8+j]; C/D: col=lane&15, row=kq*4+reg.
// ---------------------------------------------------------------------------
__global__ __launch_bounds__(256, 3) void k0_dot_table(
    const float* __restrict__ emb,      // (TR, 768)
    const short8* __restrict__ bfrag,   // (KI, 8, 64)
    float*       __restrict__ dt)       // (TR, 128)
{
    __shared__ float Abuf[2][128][32];  // 2 x 16 KB

    const int tid  = threadIdx.x;
    const int wave = tid >> 6;
    const int lane = tid & 63;
    const int mrow = lane & 15;
    const int kq   = lane >> 4;
    const int rbase = blockIdx.x * 128;

    // --- staging: wave w stages rows w*32..w*32+31; instr p covers 8 rows.
    // lane l: row_off = l>>3, slot s = l&7 -> global col16 = s ^ row_off
    const int srow = lane >> 3;              // 0..7
    const int sc16 = (lane & 7) ^ srow;      // swizzled col16 within k-slice
    const float* gb[4];
    #pragma unroll
    for (int p = 0; p < 4; ++p) {
        int rg = rbase + wave * 32 + p * 8 + srow;
        if (rg >= TR) rg = TR - 1;           // duplicate-read clamp (stores guarded)
        gb[p] = emb + (size_t)rg * E + sc16 * 4;
    }

    // --- fragment read offsets (floats): row = wave*32 + rt*16 + mrow,
    // half h wants col16 = kq*2+h stored at slot (kq*2+h)^(mrow&7)
    const int r7 = mrow & 7;
    const int f0 = (wave * 32 + mrow) * 32 + (((kq * 2)     ^ r7) << 2);
    const int f1 = (wave * 32 + mrow) * 32 + (((kq * 2 + 1) ^ r7) << 2);
    const float* Af = &Abuf[0][0][0];

    f32x4 acc[2][8];
    #pragma unroll
    for (int i = 0; i < 2; ++i)
        #pragma unroll
        for (int j = 0; j < 8; ++j)
            acc[i][j] = f32x4{0.f, 0.f, 0.f, 0.f};

    // prologue: DMA k-slice 0 into buf 0
    #pragma unroll
    for (int p = 0; p < 4; ++p)
        gl_lds16(gb[p], &Abuf[0][wave * 32 + p * 8][0]);
    __syncthreads();

    for (int kk = 0; kk < KI; ++kk) {
        const int buf = kk & 1;

        // issue DMA for next slice into the other buffer (no VGPR round-trip)
        if (kk + 1 < KI) {
            #pragma unroll
            for (int p = 0; p < 4; ++p)
                gl_lds16(gb[p] + (kk + 1) * 32, &Abuf[buf ^ 1][wave * 32 + p * 8][0]);
        }

        // A frags from LDS (fp32, swizzled, 2-way max conflicts) + cvt
        const float* Ab = Af + buf * 4096;
        const float4 x0 = *(const float4*)(Ab + f0);
        const float4 x1 = *(const float4*)(Ab + f1);
        const float4 y0 = *(const float4*)(Ab + f0 + 512);   // rt=1: +16 rows
        const float4 y1 = *(const float4*)(Ab + f1 + 512);
        const short8 A0 = pack8(x0, x1);
        const short8 A1 = pack8(y0, y1);

        // B frags: coalesced 16 B/lane, L2-hot
        short8 Bf[8];
        #pragma unroll
        for (int ct = 0; ct < 8; ++ct)
            Bf[ct] = bfrag[(kk * 8 + ct) * 64 + lane];

        #pragma unroll
        for (int ct = 0; ct < 8; ++ct) {
            acc[0][ct] = __builtin_amdgcn_mfma_f32_16x16x32_bf16(A0, Bf[ct], acc[0][ct], 0, 0, 0);
            acc[1][ct] = __builtin_amdgcn_mfma_f32_16x16x32_bf16(A1, Bf[ct], acc[1][ct], 0, 0, 0);
        }

        // drains DMA (vmcnt) + orders WAR on buf before next overwrite
        __syncthreads();
    }

    // epilogue: wave w owns rows w*32..w*32+31
    #pragma unroll
    for (int rt = 0; rt < 2; ++rt) {
        const int orow = rbase + wave * 32 + rt * 16 + kq * 4;
        #pragma unroll
        for (int r = 0; r < 4; ++r) {
            if (orow + r < TR) {
                float* o = dt + (size_t)(orow + r) * 128 + mrow;
                #pragma unroll
                for (int ct = 0; ct < 8; ++ct) o[ct * 16] = acc[rt][ct][r];
            }
        }
    }
}

// ---------------------------------------------------------------------------
// k1: sum1[b,m] = sum_p att[b,m*64+p] * dt[ids[b,m*64+p]][b*16 + m%16]
// ---------------------------------------------------------------------------
__global__ __launch_bounds__(256) void k1_bagdot(
    const float* __restrict__ dt,      // (TR, 128)
    const int*   __restrict__ ids,     // (B, LL)
    const float* __restrict__ att,     // (B, LL)
    float*       __restrict__ sum1)    // (B*M)
{
    const int seg  = blockIdx.x * 4 + (threadIdx.x >> 6);
    const int lane = threadIdx.x & 63;
    const int b = seg >> 9;
    const int m = seg & 511;
    const int n = (b << 4) | (m & 15);

    const size_t base = (size_t)b * LL + (size_t)m * P;
    const int   id = ids[base + lane];
    const float a  = att[base + lane];
    float v = a * dt[(size_t)id * 128 + n];

    #pragma unroll
    for (int off = 32; off > 0; off >>= 1)
        v += __shfl_down(v, off, 64);
    if (lane == 0) sum1[seg] = v;
}

// ---------------------------------------------------------------------------
// k2: per-batch fused: span_scores -> softmax(S) -> softmax(M) -> cand,
// branch-free dedup over duplicate qids, denominator of the 1M softmax,
// owner values sval = exp(sum_dupes)*invden. No global atomics.
// ---------------------------------------------------------------------------
__global__ __launch_bounds__(512) void k2_fused(
    const float* __restrict__ sum1,    // (B, 512)
    const float* __restrict__ span,    // (B, 16, 768)
    const float* __restrict__ spanW,   // (768)
    const float* __restrict__ spanb,   // (1)
    const int*   __restrict__ qids,    // (B, 512)
    float*       __restrict__ sval,    // (B, 512) owner value or 0
    float*       __restrict__ invden)  // (B)
{
    const int b = blockIdx.x;
    const int t = threadIdx.x;

    __shared__ float ls[512];
    __shared__ float cs[512];
    __shared__ int   qs[512];
    __shared__ float ss[16];
    __shared__ float inv_s;

    // span_scores: 16 groups of 32 threads
    {
        const int s = t >> 5, j = t & 31;
        const float* sp = span + (size_t)(b * S + s) * E;
        float partial = 0.f;
        for (int e = j; e < E; e += 32) partial = fmaf(sp[e], spanW[e], partial);
        #pragma unroll
        for (int off = 16; off > 0; off >>= 1) partial += __shfl_down(partial, off, 32);
        if (j == 0) ss[s] = partial + spanb[0];
    }

    const float v = sum1[b * M + t];
    ls[t] = v;
    qs[t] = qids[b * M + t];
    __syncthreads();

    // softmax over s (16 values at stride 32) for this thread's column
    const int c = t & 31;
    float mx = -1e30f;
    #pragma unroll
    for (int s2 = 0; s2 < S; ++s2) mx = fmaxf(mx, ls[s2 * 32 + c]);
    float den = 0.f;
    #pragma unroll
    for (int s2 = 0; s2 < S; ++s2) den += expf(ls[s2 * 32 + c] - mx);
    const float m2 = ss[t >> 5] * (expf(v - mx) / den);
    __syncthreads();

    // softmax over 512
    ls[t] = m2; __syncthreads();
    for (int off = 256; off > 0; off >>= 1) {
        if (t < off) ls[t] = fmaxf(ls[t], ls[t + off]);
        __syncthreads();
    }
    const float bigM = ls[0];
    __syncthreads();
    const float ex = expf(m2 - bigM);
    ls[t] = ex; __syncthreads();
    for (int off = 256; off > 0; off >>= 1) {
        if (t < off) ls[t] += ls[t + off];
        __syncthreads();
    }
    const float cand = ex / ls[0];
    __syncthreads();

    cs[t] = cand; __syncthreads();

    // branch-free dedup scan (LDS broadcast reads, fully pipelined)
    const int myq = qs[t];
    float dsum = 0.f;
    int first = 512;
    #pragma unroll 8
    for (int j = 0; j < 512; ++j) {
        const bool match = (qs[j] == myq);
        dsum += match ? cs[j] : 0.f;
        if (match && j < first) first = j;
    }
    const bool owner = (first == t) && (myq < NE);
    const float ev = owner ? expf(dsum) : 1.f;

    ls[t] = owner ? (ev - 1.f) : 0.f;
    __syncthreads();
    for (int off = 256; off > 0; off >>= 1) {
        if (t < off) ls[t] += ls[t + off];
        __syncthreads();
    }
    if (t == 0) {
        const float iv = 1.f / (1.0e6f + ls[0]);
        invden[b] = iv;
        inv_s = iv;
    }
    __syncthreads();

    sval[b * M + t] = owner ? ev * inv_s : 0.f;
}

// ---------------------------------------------------------------------------
// k3: out[b][i] = invden[b] everywhere (write-only, float4). exp(0)=1 baseline.
// ---------------------------------------------------------------------------
__global__ __launch_bounds__(256) void k3_fill(
    float* __restrict__ out, const float* __restrict__ invden)
{
    const int i = blockIdx.x * 256 + threadIdx.x;   // over B*NE/4 = 2M float4
    if (i >= (B * NE) / 4) return;
    const float v = invden[i / (NE / 4)];
    reinterpret_cast<float4*>(out)[i] = make_float4(v, v, v, v);
}

// ---------------------------------------------------------------------------
// k4: scatter owner values over the fill (<=4096 dword stores).
// ---------------------------------------------------------------------------
__global__ __launch_bounds__(512) void k4_scatter(
    const float* __restrict__ sval, const int* __restrict__ qids,
    float* __restrict__ out)
{
    const int b = blockIdx.x, t = threadIdx.x;
    const float v = sval[b * M + t];
    const int   q = qids[b * M + t];
    if (v > 0.f && q < NE) out[(size_t)b * NE + q] = v;
}

extern "C" void kernel_launch(void* const* d_in, const int* in_sizes, int n_in,
                              void* d_out, int out_size, void* d_ws, size_t ws_size,
                              hipStream_t stream)
{
    (void)in_sizes; (void)n_in; (void)out_size; (void)ws_size;

    const float* span_embs = (const float*)d_in[0];  // (B,S,E)
    const int*   ids       = (const int*)  d_in[1];  // (B,LL)
    // d_in[2]: offsets_tr — fixed arange(M)*P structure, not needed
    const float* att       = (const float*)d_in[3];  // (B,LL)
    const int*   qids      = (const int*)  d_in[4];  // (B,M)
    const float* emb       = (const float*)d_in[5];  // (T,E)
    const float* spanW     = (const float*)d_in[6];  // (E)
    const float* spanb     = (const float*)d_in[7];  // (1)

    float* out = (float*)d_out;

    // workspace layout (~51.5 MB)
    float*  dt     = (float*)d_ws;                 // TR*128 floats = 51.2 MB
    float*  sum1   = dt + (size_t)TR * 128;        // 4096
    float*  sval   = sum1 + B * M;                 // 4096
    float*  invden = sval + B * M;                 // 8 (+pad)
    short8* bfrag  = (short8*)(invden + 64);       // 12288 * 16 B = 196 KB

    k_pre_bfrag<<<(KI * 8 * 64 + 255) / 256, 256, 0, stream>>>(span_embs, bfrag);
    k0_dot_table<<<(TR + 127) / 128, 256, 0, stream>>>(emb, bfrag, dt);
    k1_bagdot<<<(B * M) / 4, 256, 0, stream>>>(dt, ids, att, sum1);
    k2_fused<<<B, 512, 0, stream>>>(sum1, span_embs, spanW, spanb, qids, sval, invden);
    k3_fill<<<((B * NE / 4) + 255) / 256, 256, 0, stream>>>(out, invden);
    k4_scatter<<<B, 512, 0, stream>>>(sval, qids, out);
}